// Round 2
// baseline (614.266 us; speedup 1.0000x reference)
//
#include <hip/hip_runtime.h>
#include <math.h>

// ---------------------------------------------------------------------------
// VariableTransformerBlock on MI355X (gfx950)
// B=2, S=2048, E=1024, H=16, D=64, F=4096. fp32 in/out, bf16 MFMA internally.
// ---------------------------------------------------------------------------

typedef __attribute__((ext_vector_type(8))) short short8;   // 8 x bf16 (4 VGPRs)
typedef __attribute__((ext_vector_type(4))) float f32x4;    // MFMA accumulator

__device__ __forceinline__ unsigned short f2bf(float f) {
  unsigned int u = __float_as_uint(f);
  u += 0x7fffu + ((u >> 16) & 1u);   // round-to-nearest-even
  return (unsigned short)(u >> 16);
}

// async global -> LDS, 16 B per lane. LDS dest is wave-uniform base + lane*16.
__device__ __forceinline__ void async16(const void* g, void* l) {
  __builtin_amdgcn_global_load_lds(
      (const __attribute__((address_space(1))) unsigned int*)g,
      (__attribute__((address_space(3))) unsigned int*)l, 16, 0, 0);
}

// ---------------------------------------------------------------------------
// fp32 -> bf16 conversion. n4 = number of float4 groups.
// ---------------------------------------------------------------------------
__global__ __launch_bounds__(256) void conv_f32_bf16(const float* __restrict__ in,
                                                     unsigned short* __restrict__ out,
                                                     int n4) {
  int i = blockIdx.x * 256 + threadIdx.x;
  if (i < n4) {
    float4 v = ((const float4*)in)[i];
    ushort4 u;
    u.x = f2bf(v.x); u.y = f2bf(v.y); u.z = f2bf(v.z); u.w = f2bf(v.w);
    ((ushort4*)out)[i] = u;
  }
}

// ---------------------------------------------------------------------------
// LayerNorm: one block per row of 1024 fp32, writes bf16.
// ---------------------------------------------------------------------------
__global__ __launch_bounds__(256) void ln_kernel(const float* __restrict__ x,
                                                 const float* __restrict__ g,
                                                 const float* __restrict__ b,
                                                 unsigned short* __restrict__ out) {
  int row = blockIdx.x;
  int t = threadIdx.x;
  const float4* x4 = (const float4*)(x + (size_t)row * 1024);
  float4 v = x4[t];
  float s1 = v.x + v.y + v.z + v.w;
  float s2 = v.x * v.x + v.y * v.y + v.z * v.z + v.w * v.w;
  for (int off = 1; off < 64; off <<= 1) {
    s1 += __shfl_xor(s1, off, 64);
    s2 += __shfl_xor(s2, off, 64);
  }
  __shared__ float r1[4], r2[4];
  int w = t >> 6, lane = t & 63;
  if (lane == 0) { r1[w] = s1; r2[w] = s2; }
  __syncthreads();
  s1 = r1[0] + r1[1] + r1[2] + r1[3];
  s2 = r2[0] + r2[1] + r2[2] + r2[3];
  float mu = s1 * (1.0f / 1024.0f);
  float var = s2 * (1.0f / 1024.0f) - mu * mu;
  float rstd = rsqrtf(var + 1e-5f);
  int c = t * 4;
  float4 gv = ((const float4*)g)[t];
  float4 bv = ((const float4*)b)[t];
  unsigned short* o = out + (size_t)row * 1024 + c;
  o[0] = f2bf((v.x - mu) * rstd * gv.x + bv.x);
  o[1] = f2bf((v.y - mu) * rstd * gv.y + bv.y);
  o[2] = f2bf((v.z - mu) * rstd * gv.z + bv.z);
  o[3] = f2bf((v.w - mu) * rstd * gv.w + bv.w);
}

// ---------------------------------------------------------------------------
// GEMM: C[M,N] = A[M,K](bf16) @ W[N,K](bf16)^T + bias.
// 128x128 tile, 4 waves 2x2, each 64x64 (4x4 of 16x16x32 MFMA).
// m97 structure: global_load_lds width-16 staging, unpadded 128x32 LDS tiles.
// MODE 0: QKV epilogue -> q(B,H,S,D), k(B,H,S,D), vT(B,H,D,S), all bf16
// MODE 1: fp32 out = acc + bias + resid
// MODE 2: bf16 out = gelu_exact(acc + bias)
// ---------------------------------------------------------------------------
template <int MODE>
__global__ __launch_bounds__(256) void gemm_bt(
    const unsigned short* __restrict__ A, const unsigned short* __restrict__ W,
    const float* __restrict__ bias, int M, int N, int K,
    const float* __restrict__ resid, float* __restrict__ out_f32,
    unsigned short* __restrict__ out_bf16,
    unsigned short* __restrict__ qbp, unsigned short* __restrict__ kbp,
    unsigned short* __restrict__ vtb) {
  __shared__ __attribute__((aligned(16))) unsigned short As[128 * 32];
  __shared__ __attribute__((aligned(16))) unsigned short Ws[128 * 32];
  int tid = threadIdx.x;
  int w = tid >> 6, lane = tid & 63, quad = lane >> 4, l16 = lane & 15;
  int wrow = w >> 1, wcol = w & 1;
  int m0 = blockIdx.y * 128, n0 = blockIdx.x * 128;

  // staging: wave w, inst i covers LDS bytes [w*1024 + i*4096, +1024)
  // -> row = w*16 + i*64 + (lane>>2), col = (lane&3)*8
  const unsigned short* Ag = A + (size_t)(m0 + w * 16 + (lane >> 2)) * K + (lane & 3) * 8;
  const unsigned short* Wg = W + (size_t)(n0 + w * 16 + (lane >> 2)) * K + (lane & 3) * 8;
  unsigned short* Asl = As + w * 512;
  unsigned short* Wsl = Ws + w * 512;
  const size_t K64 = (size_t)64 * K;

  f32x4 acc[4][4] = {};

  for (int k0 = 0; k0 < K; k0 += 32) {
    __syncthreads();                       // prior frag reads done
    async16(Ag + k0, Asl);
    async16(Ag + K64 + k0, Asl + 2048);
    async16(Wg + k0, Wsl);
    async16(Wg + K64 + k0, Wsl + 2048);
    __syncthreads();                       // drains vmcnt(0) -> LDS valid
    short8 af[4], bf[4];
    for (int i = 0; i < 4; i++)
      af[i] = *(const short8*)(As + (wrow * 64 + i * 16 + l16) * 32 + quad * 8);
    for (int j = 0; j < 4; j++)
      bf[j] = *(const short8*)(Ws + (wcol * 64 + j * 16 + l16) * 32 + quad * 8);
    for (int i = 0; i < 4; i++)
      for (int j = 0; j < 4; j++)
        acc[i][j] = __builtin_amdgcn_mfma_f32_16x16x32_bf16(af[i], bf[j], acc[i][j], 0, 0, 0);
  }

  for (int j = 0; j < 4; j++) {
    int col = n0 + wcol * 64 + j * 16 + l16;
    float bv = bias[col];
    if (MODE == 0) {
      int which = col >> 10;
      int rr2 = col & 1023;
      int hh = rr2 >> 6, d = rr2 & 63;
      for (int i = 0; i < 4; i++) {
        int row0 = m0 + wrow * 64 + i * 16 + quad * 4;
        int bb = row0 >> 11, s = row0 & 2047;
        int bh = bb * 16 + hh;
        if (which == 2) {
          ushort4 pk;
          pk.x = f2bf(acc[i][j][0] + bv);
          pk.y = f2bf(acc[i][j][1] + bv);
          pk.z = f2bf(acc[i][j][2] + bv);
          pk.w = f2bf(acc[i][j][3] + bv);
          *(ushort4*)(vtb + ((size_t)bh * 64 + d) * 2048 + s) = pk;  // s%4==0 -> 8B aligned
        } else {
          unsigned short* dst = (which == 0 ? qbp : kbp) + ((size_t)bh * 2048 + s) * 64 + d;
          for (int r = 0; r < 4; r++) dst[(size_t)r * 64] = f2bf(acc[i][j][r] + bv);
        }
      }
    } else {
      for (int i = 0; i < 4; i++) {
        int row0 = m0 + wrow * 64 + i * 16 + quad * 4;
        for (int r = 0; r < 4; r++) {
          int row = row0 + r;
          float v = acc[i][j][r] + bv;
          if (MODE == 1) {
            out_f32[(size_t)row * N + col] = v + resid[(size_t)row * N + col];
          } else {
            float gval = 0.5f * v * (1.0f + erff(v * 0.70710678118f));
            out_bf16[(size_t)row * N + col] = f2bf(gval);
          }
        }
      }
    }
  }
}

// ---------------------------------------------------------------------------
// Flash attention, register-resident online softmax.
// Grid (S/64, B*H), block 256 (4 waves). Wave w owns Q rows q0+w*16..+16 and
// iterates key chunks of 256. S^T = K·Q^T per wave: 16 MFMA tiles in regs;
// C-layout: key = c0+t*16+quad*4+r, qrow = l16 -> per-lane row state, softmax
// reduction = 2 shuffles (xor 16,32). P (bf16) goes through a per-wave LDS
// buffer (b32 packed writes, LDP=264 -> <=2-way bank aliasing = free) to reach
// MFMA A-layout for PV. No __syncthreads anywhere (per-wave LDS only).
// ---------------------------------------------------------------------------
#define LDP 264

__global__ __launch_bounds__(256) void attn_kernel(const unsigned short* __restrict__ qb,
                                                   const unsigned short* __restrict__ kb,
                                                   const unsigned short* __restrict__ vtb,
                                                   unsigned short* __restrict__ ob) {
  __shared__ __attribute__((aligned(16))) unsigned short pball[4][16 * LDP];
  int tid = threadIdx.x;
  int w = tid >> 6, lane = tid & 63, quad = lane >> 4, l16 = lane & 15;
  int bh = blockIdx.y;
  int q0 = blockIdx.x * 64 + w * 16;

  const unsigned short* qbase = qb + ((size_t)bh * 2048 + q0) * 64;
  const unsigned short* kbase = kb + (size_t)bh * 2048 * 64;
  const unsigned short* vbase = vtb + (size_t)bh * 64 * 2048;
  unsigned short* pw = pball[w];

  // Q as B-operand: B[k=quad*8+j][n=l16] = Q[qrow=l16][d=quad*8+j (+32)]
  short8 qf0 = *(const short8*)(qbase + l16 * 64 + quad * 8);
  short8 qf1 = *(const short8*)(qbase + l16 * 64 + 32 + quad * 8);

  float m_run = -3e38f, l_run = 0.0f;
  f32x4 oacc[4] = {};
  const float sc2 = 0.125f * 1.44269504089f;  // 1/sqrt(64) * log2(e)

  for (int c0 = 0; c0 < 2048; c0 += 256) {
    // ---- S^T tiles: s[t] rows = keys t*16+quad*4+r, col = qrow l16
    f32x4 s[16];
    for (int t = 0; t < 16; t++) {
      const unsigned short* kp = kbase + (size_t)(c0 + t * 16 + l16) * 64 + quad * 8;
      short8 kf0 = *(const short8*)kp;
      short8 kf1 = *(const short8*)(kp + 32);
      f32x4 z = {};
      z = __builtin_amdgcn_mfma_f32_16x16x32_bf16(kf0, qf0, z, 0, 0, 0);
      z = __builtin_amdgcn_mfma_f32_16x16x32_bf16(kf1, qf1, z, 0, 0, 0);
      s[t] = z;
    }
    // ---- row max (row = l16, each lane holds 64 of its row's 256 keys)
    float mx = -3e38f;
    for (int t = 0; t < 16; t++)
      for (int r = 0; r < 4; r++) mx = fmaxf(mx, s[t][r]);
    mx *= sc2;
    mx = fmaxf(mx, __shfl_xor(mx, 16, 64));
    mx = fmaxf(mx, __shfl_xor(mx, 32, 64));
    float mnew = fmaxf(m_run, mx);
    float alpha = exp2f(m_run - mnew);
    // ---- exp, pack bf16 pairs, accumulate row sum
    float rsum = 0.0f;
    unsigned short* pr = pw + l16 * LDP;
    for (int t = 0; t < 16; t++) {
      float p0 = exp2f(fmaf(s[t][0], sc2, -mnew));
      float p1 = exp2f(fmaf(s[t][1], sc2, -mnew));
      float p2 = exp2f(fmaf(s[t][2], sc2, -mnew));
      float p3 = exp2f(fmaf(s[t][3], sc2, -mnew));
      rsum += (p0 + p1) + (p2 + p3);
      unsigned int pk01 = (unsigned int)f2bf(p0) | ((unsigned int)f2bf(p1) << 16);
      unsigned int pk23 = (unsigned int)f2bf(p2) | ((unsigned int)f2bf(p3) << 16);
      *(unsigned int*)(pr + t * 16 + quad * 4) = pk01;       // P[qrow=l16][key]
      *(unsigned int*)(pr + t * 16 + quad * 4 + 2) = pk23;
    }
    rsum += __shfl_xor(rsum, 16, 64);
    rsum += __shfl_xor(rsum, 32, 64);
    l_run = l_run * alpha + rsum;
    m_run = mnew;
    // ---- rescale O by alpha of row quad*4+r (bpermute from lane quad*4+r)
    float alr[4];
    for (int r = 0; r < 4; r++) alr[r] = __shfl(alpha, quad * 4 + r, 64);
    for (int j = 0; j < 4; j++)
      for (int r = 0; r < 4; r++) oacc[j][r] *= alr[r];
    // all P writes of this wave complete before A-frag reads (same-wave DS order)
    asm volatile("s_waitcnt lgkmcnt(0)" ::: "memory");
    // ---- PV: A = P[qrow=l16][k=ks*32+quad*8+j], B = V^T[d][key]
    for (int ks = 0; ks < 8; ks++) {
      short8 af = *(const short8*)(pw + l16 * LDP + ks * 32 + quad * 8);
      for (int j = 0; j < 4; j++) {
        short8 vf = *(const short8*)(vbase + (size_t)(j * 16 + l16) * 2048 + c0 + ks * 32 + quad * 8);
        oacc[j] = __builtin_amdgcn_mfma_f32_16x16x32_bf16(af, vf, oacc[j], 0, 0, 0);
      }
    }
    asm volatile("" ::: "memory");  // keep this chunk's reads before next chunk's writes
  }

  float linv[4];
  for (int r = 0; r < 4; r++) linv[r] = 1.0f / __shfl(l_run, quad * 4 + r, 64);
  int bb = bh >> 4, hh = bh & 15;
  for (int j = 0; j < 4; j++)
    for (int r = 0; r < 4; r++) {
      size_t tok = (size_t)bb * 2048 + q0 + quad * 4 + r;
      ob[tok * 1024 + hh * 64 + j * 16 + l16] = f2bf(oacc[j][r] * linv[r]);
    }
}

// ---------------------------------------------------------------------------
// Launch
// ---------------------------------------------------------------------------
extern "C" void kernel_launch(void* const* d_in, const int* in_sizes, int n_in,
                              void* d_out, int out_size, void* d_ws, size_t ws_size,
                              hipStream_t stream) {
  (void)in_sizes; (void)n_in; (void)out_size; (void)ws_size;
  const float* x     = (const float*)d_in[0];
  const float* qkv_w = (const float*)d_in[1];
  const float* qkv_b = (const float*)d_in[2];
  const float* out_w = (const float*)d_in[3];
  const float* out_b = (const float*)d_in[4];
  const float* ff1_w = (const float*)d_in[5];
  const float* ff1_b = (const float*)d_in[6];
  const float* ff2_w = (const float*)d_in[7];
  const float* ff2_b = (const float*)d_in[8];
  const float* ln1_g = (const float*)d_in[9];
  const float* ln1_b = (const float*)d_in[10];
  const float* ln2_g = (const float*)d_in[11];
  const float* ln2_b = (const float*)d_in[12];
  float* out = (float*)d_out;
  char* ws = (char*)d_ws;

  const int M = 4096;  // B*S

  // ws layout (bytes)
  unsigned short* WQ = (unsigned short*)(ws + 0);           //  6,291,456
  unsigned short* WO = (unsigned short*)(ws + 6291456);     //  2,097,152
  unsigned short* W1 = (unsigned short*)(ws + 8388608);     //  8,388,608
  unsigned short* W2 = (unsigned short*)(ws + 16777216);    //  8,388,608
  unsigned short* Hb = (unsigned short*)(ws + 25165824);    //  8,388,608
  unsigned short* Qb = (unsigned short*)(ws + 33554432);    //  8,388,608
  unsigned short* Kb = (unsigned short*)(ws + 41943040);    //  8,388,608
  unsigned short* VT = (unsigned short*)(ws + 50331648);    //  8,388,608
  unsigned short* Ob = (unsigned short*)(ws + 58720256);    //  8,388,608
  float*          X1 = (float*)(ws + 67108864);             // 16,777,216
  unsigned short* Gb = (unsigned short*)(ws + 33554432);    // reuses Q/K/VT/O after out-proj
  // total ws footprint: 83,886,080 bytes (80 MB)

  // 1. weight conversions fp32 -> bf16
  conv_f32_bf16<<<3072, 256, 0, stream>>>(qkv_w, WQ, 786432);
  conv_f32_bf16<<<1024, 256, 0, stream>>>(out_w, WO, 262144);
  conv_f32_bf16<<<4096, 256, 0, stream>>>(ff1_w, W1, 1048576);
  conv_f32_bf16<<<4096, 256, 0, stream>>>(ff2_w, W2, 1048576);

  // 2. LN1: x -> Hb (bf16)
  ln_kernel<<<4096, 256, 0, stream>>>(x, ln1_g, ln1_b, Hb);

  // 3. QKV GEMM -> scatter q/k/vT
  gemm_bt<0><<<dim3(24, 32), 256, 0, stream>>>(Hb, WQ, qkv_b, M, 3072, 1024,
                                               nullptr, nullptr, nullptr, Qb, Kb, VT);

  // 4. attention -> Ob bf16 (B,S,E)
  attn_kernel<<<dim3(32, 32), 256, 0, stream>>>(Qb, Kb, VT, Ob);

  // 5. out-proj + residual: X1 = x + Ob@WO^T + out_b (fp32)
  gemm_bt<1><<<dim3(8, 32), 256, 0, stream>>>(Ob, WO, out_b, M, 1024, 1024,
                                              x, X1, nullptr, nullptr, nullptr, nullptr);

  // 6. LN2: X1 -> Hb (bf16)
  ln_kernel<<<4096, 256, 0, stream>>>(X1, ln2_g, ln2_b, Hb);

  // 7. FF1 + exact GELU: Gb = gelu(Hb@W1^T + ff1_b) bf16 (4096x4096)
  gemm_bt<2><<<dim3(32, 32), 256, 0, stream>>>(Hb, W1, ff1_b, M, 4096, 1024,
                                               nullptr, nullptr, Gb, nullptr, nullptr, nullptr);

  // 8. FF2 + residual: out = X1 + Gb@W2^T + ff2_b (fp32)
  gemm_bt<1><<<dim3(8, 32), 256, 0, stream>>>(Gb, W2, ff2_b, M, 1024, 4096,
                                              X1, out, nullptr, nullptr, nullptr, nullptr);
}

// Round 3
// 451.267 us; speedup vs baseline: 1.3612x; 1.3612x over previous
//
#include <hip/hip_runtime.h>
#include <math.h>

// ---------------------------------------------------------------------------
// VariableTransformerBlock on MI355X (gfx950)
// B=2, S=2048, E=1024, H=16, D=64, F=4096. fp32 in/out, bf16 MFMA internally.
// ---------------------------------------------------------------------------

typedef __attribute__((ext_vector_type(8))) short short8;   // 8 x bf16 (4 VGPRs)
typedef __attribute__((ext_vector_type(4))) float f32x4;    // MFMA accumulator

__device__ __forceinline__ unsigned short f2bf(float f) {
  unsigned int u = __float_as_uint(f);
  u += 0x7fffu + ((u >> 16) & 1u);   // round-to-nearest-even
  return (unsigned short)(u >> 16);
}

// async global -> LDS, 16 B per lane. LDS dest is wave-uniform base + lane*16.
__device__ __forceinline__ void async16(const void* g, void* l) {
  __builtin_amdgcn_global_load_lds(
      (const __attribute__((address_space(1))) unsigned int*)g,
      (__attribute__((address_space(3))) unsigned int*)l, 16, 0, 0);
}

// ---------------------------------------------------------------------------
// fp32 -> bf16 conversion. n4 = number of float4 groups.
// ---------------------------------------------------------------------------
__global__ __launch_bounds__(256) void conv_f32_bf16(const float* __restrict__ in,
                                                     unsigned short* __restrict__ out,
                                                     int n4) {
  int i = blockIdx.x * 256 + threadIdx.x;
  if (i < n4) {
    float4 v = ((const float4*)in)[i];
    ushort4 u;
    u.x = f2bf(v.x); u.y = f2bf(v.y); u.z = f2bf(v.z); u.w = f2bf(v.w);
    ((ushort4*)out)[i] = u;
  }
}

// ---------------------------------------------------------------------------
// LayerNorm: one block per row of 1024 fp32, writes bf16.
// ---------------------------------------------------------------------------
__global__ __launch_bounds__(256) void ln_kernel(const float* __restrict__ x,
                                                 const float* __restrict__ g,
                                                 const float* __restrict__ b,
                                                 unsigned short* __restrict__ out) {
  int row = blockIdx.x;
  int t = threadIdx.x;
  const float4* x4 = (const float4*)(x + (size_t)row * 1024);
  float4 v = x4[t];
  float s1 = v.x + v.y + v.z + v.w;
  float s2 = v.x * v.x + v.y * v.y + v.z * v.z + v.w * v.w;
  for (int off = 1; off < 64; off <<= 1) {
    s1 += __shfl_xor(s1, off, 64);
    s2 += __shfl_xor(s2, off, 64);
  }
  __shared__ float r1[4], r2[4];
  int w = t >> 6, lane = t & 63;
  if (lane == 0) { r1[w] = s1; r2[w] = s2; }
  __syncthreads();
  s1 = r1[0] + r1[1] + r1[2] + r1[3];
  s2 = r2[0] + r2[1] + r2[2] + r2[3];
  float mu = s1 * (1.0f / 1024.0f);
  float var = s2 * (1.0f / 1024.0f) - mu * mu;
  float rstd = rsqrtf(var + 1e-5f);
  int c = t * 4;
  float4 gv = ((const float4*)g)[t];
  float4 bv = ((const float4*)b)[t];
  unsigned short* o = out + (size_t)row * 1024 + c;
  o[0] = f2bf((v.x - mu) * rstd * gv.x + bv.x);
  o[1] = f2bf((v.y - mu) * rstd * gv.y + bv.y);
  o[2] = f2bf((v.z - mu) * rstd * gv.z + bv.z);
  o[3] = f2bf((v.w - mu) * rstd * gv.w + bv.w);
}

// ---------------------------------------------------------------------------
// GEMM: C[M,N] = A[M,K](bf16) @ W[N,K](bf16)^T + bias.
// 128x128 tile, 4 waves 2x2, each 64x64 (4x4 of 16x16x32 MFMA).
// m97 structure: global_load_lds width-16 staging, unpadded 128x32 LDS tiles.
// MODE 0: QKV epilogue -> q(B,H,S,D), k(B,H,S,D), vT(B,H,D,S), all bf16
// MODE 1: fp32 out = acc + bias + resid
// MODE 2: bf16 out = gelu_exact(acc + bias)
// ---------------------------------------------------------------------------
template <int MODE>
__global__ __launch_bounds__(256) void gemm_bt(
    const unsigned short* __restrict__ A, const unsigned short* __restrict__ W,
    const float* __restrict__ bias, int M, int N, int K,
    const float* __restrict__ resid, float* __restrict__ out_f32,
    unsigned short* __restrict__ out_bf16,
    unsigned short* __restrict__ qbp, unsigned short* __restrict__ kbp,
    unsigned short* __restrict__ vtb) {
  __shared__ __attribute__((aligned(16))) unsigned short As[128 * 32];
  __shared__ __attribute__((aligned(16))) unsigned short Ws[128 * 32];
  int tid = threadIdx.x;
  int w = tid >> 6, lane = tid & 63, quad = lane >> 4, l16 = lane & 15;
  int wrow = w >> 1, wcol = w & 1;
  int m0 = blockIdx.y * 128, n0 = blockIdx.x * 128;

  const unsigned short* Ag = A + (size_t)(m0 + w * 16 + (lane >> 2)) * K + (lane & 3) * 8;
  const unsigned short* Wg = W + (size_t)(n0 + w * 16 + (lane >> 2)) * K + (lane & 3) * 8;
  unsigned short* Asl = As + w * 512;
  unsigned short* Wsl = Ws + w * 512;
  const size_t K64 = (size_t)64 * K;

  f32x4 acc[4][4] = {};

  for (int k0 = 0; k0 < K; k0 += 32) {
    __syncthreads();
    async16(Ag + k0, Asl);
    async16(Ag + K64 + k0, Asl + 2048);
    async16(Wg + k0, Wsl);
    async16(Wg + K64 + k0, Wsl + 2048);
    __syncthreads();
    short8 af[4], bf[4];
    for (int i = 0; i < 4; i++)
      af[i] = *(const short8*)(As + (wrow * 64 + i * 16 + l16) * 32 + quad * 8);
    for (int j = 0; j < 4; j++)
      bf[j] = *(const short8*)(Ws + (wcol * 64 + j * 16 + l16) * 32 + quad * 8);
    for (int i = 0; i < 4; i++)
      for (int j = 0; j < 4; j++)
        acc[i][j] = __builtin_amdgcn_mfma_f32_16x16x32_bf16(af[i], bf[j], acc[i][j], 0, 0, 0);
  }

  for (int j = 0; j < 4; j++) {
    int col = n0 + wcol * 64 + j * 16 + l16;
    float bv = bias[col];
    if (MODE == 0) {
      int which = col >> 10;
      int rr2 = col & 1023;
      int hh = rr2 >> 6, d = rr2 & 63;
      for (int i = 0; i < 4; i++) {
        int row0 = m0 + wrow * 64 + i * 16 + quad * 4;
        int bb = row0 >> 11, s = row0 & 2047;
        int bh = bb * 16 + hh;
        if (which == 2) {
          ushort4 pk;
          pk.x = f2bf(acc[i][j][0] + bv);
          pk.y = f2bf(acc[i][j][1] + bv);
          pk.z = f2bf(acc[i][j][2] + bv);
          pk.w = f2bf(acc[i][j][3] + bv);
          *(ushort4*)(vtb + ((size_t)bh * 64 + d) * 2048 + s) = pk;
        } else {
          unsigned short* dst = (which == 0 ? qbp : kbp) + ((size_t)bh * 2048 + s) * 64 + d;
          for (int r = 0; r < 4; r++) dst[(size_t)r * 64] = f2bf(acc[i][j][r] + bv);
        }
      }
    } else {
      for (int i = 0; i < 4; i++) {
        int row0 = m0 + wrow * 64 + i * 16 + quad * 4;
        for (int r = 0; r < 4; r++) {
          int row = row0 + r;
          float v = acc[i][j][r] + bv;
          if (MODE == 1) {
            out_f32[(size_t)row * N + col] = v + resid[(size_t)row * N + col];
          } else {
            float gval = 0.5f * v * (1.0f + erff(v * 0.70710678118f));
            out_bf16[(size_t)row * N + col] = f2bf(gval);
          }
        }
      }
    }
  }
}

// ---------------------------------------------------------------------------
// Flash attention v3: LDS-staged K/V chunks, double-buffered async prefetch.
// Grid (S/128, B*H), block 256 (4 waves). Wave w owns Q rows q0+w*32..+32
// (2 column-sets of 16). Chunk = 64 keys. K chunk (64 keys x 64 d) and
// V^T chunk (64 d x 64 keys) staged via global_load_lds with a 16B XOR
// swizzle (segment s of row r lands at slot s^(r&7)) so frag ds_read_b128s
// are <=2-way bank-aliased (free). One __syncthreads per chunk: its vmcnt(0)
// drains only the PREVIOUS chunk's prefetch -> staging overlaps compute.
// S^T = K·Q^T per set (C-layout: row=key, col=q=l16) -> softmax reduction is
// 2 shuffles; P goes through per-wave LDS (LDP=80) to A-layout for PV.
// ---------------------------------------------------------------------------
#define ALDP 80

__global__ __launch_bounds__(256) void attn_kernel(const unsigned short* __restrict__ qb,
                                                   const unsigned short* __restrict__ kb,
                                                   const unsigned short* __restrict__ vtb,
                                                   unsigned short* __restrict__ ob) {
  __shared__ __attribute__((aligned(16))) unsigned short Ks[2][64 * 64];  // 8KB/buf
  __shared__ __attribute__((aligned(16))) unsigned short Vs[2][64 * 64];  // 8KB/buf
  __shared__ __attribute__((aligned(16))) unsigned short Ps[4][2 * 16 * ALDP];

  int tid = threadIdx.x;
  int w = tid >> 6, lane = tid & 63, quad = lane >> 4, l16 = lane & 15;
  int bh = blockIdx.y;
  int q0 = blockIdx.x * 128 + w * 32;

  const unsigned short* qbase = qb + ((size_t)bh * 2048 + q0) * 64;
  const unsigned short* kbase = kb + (size_t)bh * 2048 * 64;
  const unsigned short* vbase = vtb + (size_t)bh * 64 * 2048;
  unsigned short* Pw = Ps[w];

  // staging lane geometry: one inst = 8 rows x 128B; global segment XOR'd
  int srow = lane >> 3;                       // 0..7
  int scol = ((lane & 7) ^ srow) * 8;         // shorts
  const unsigned short* kg0 = kbase + (size_t)(w * 16 + srow) * 64 + scol;
  const unsigned short* kg1 = kbase + (size_t)(w * 16 + 8 + srow) * 64 + scol;
  const unsigned short* vg0 = vbase + (size_t)(w * 16 + srow) * 2048 + scol;
  const unsigned short* vg1 = vbase + (size_t)(w * 16 + 8 + srow) * 2048 + scol;

  // Q fragments (B-operand): set u covers q rows u*16+l16; halves of d
  short8 qf[2][2];
  for (int u = 0; u < 2; u++) {
    qf[u][0] = *(const short8*)(qbase + (u * 16 + l16) * 64 + quad * 8);
    qf[u][1] = *(const short8*)(qbase + (u * 16 + l16) * 64 + 32 + quad * 8);
  }

  float m0 = -3e38f, m1 = -3e38f, l0 = 0.0f, l1 = 0.0f;
  f32x4 oacc[2][4] = {};
  const float sc2 = 0.125f * 1.44269504089f;  // 1/sqrt(64) * log2(e)
  int sw = l16 & 7;

  // prologue: stage chunk 0 into buf 0
  async16(kg0, &Ks[0][(w * 16) * 64]);
  async16(kg1, &Ks[0][(w * 16 + 8) * 64]);
  async16(vg0, &Vs[0][(w * 16) * 64]);
  async16(vg1, &Vs[0][(w * 16 + 8) * 64]);

  for (int c0 = 0; c0 < 2048; c0 += 64) {
    int buf = (c0 >> 6) & 1;
    __syncthreads();   // drains prev prefetch (vmcnt 0) + all frag reads of buf^1
    if (c0 + 64 < 2048) {
      int nb = buf ^ 1;
      async16(kg0 + (size_t)(c0 + 64) * 64, &Ks[nb][(w * 16) * 64]);
      async16(kg1 + (size_t)(c0 + 64) * 64, &Ks[nb][(w * 16 + 8) * 64]);
      async16(vg0 + c0 + 64, &Vs[nb][(w * 16) * 64]);
      async16(vg1 + c0 + 64, &Vs[nb][(w * 16 + 8) * 64]);
    }
    // ---- QK^T: K-frags read once, shared by both q-sets
    short8 kf[4][2];
    for (int t = 0; t < 4; t++) {
      const unsigned short* kr = &Ks[buf][(t * 16 + l16) * 64];
      kf[t][0] = *(const short8*)(kr + (quad ^ sw) * 8);
      kf[t][1] = *(const short8*)(kr + ((4 + quad) ^ sw) * 8);
    }
    f32x4 s[2][4];
    for (int u = 0; u < 2; u++)
      for (int t = 0; t < 4; t++) {
        f32x4 z = {0.0f, 0.0f, 0.0f, 0.0f};
        z = __builtin_amdgcn_mfma_f32_16x16x32_bf16(kf[t][0], qf[u][0], z, 0, 0, 0);
        z = __builtin_amdgcn_mfma_f32_16x16x32_bf16(kf[t][1], qf[u][1], z, 0, 0, 0);
        s[u][t] = z;
      }
    // ---- online softmax per set (lane's q-row = l16; keys t*16+quad*4+r)
    for (int u = 0; u < 2; u++) {
      float m_run = (u == 0) ? m0 : m1;
      float l_run = (u == 0) ? l0 : l1;
      float mx = -3e38f;
      for (int t = 0; t < 4; t++)
        for (int r = 0; r < 4; r++) mx = fmaxf(mx, s[u][t][r]);
      mx *= sc2;
      mx = fmaxf(mx, __shfl_xor(mx, 16, 64));
      mx = fmaxf(mx, __shfl_xor(mx, 32, 64));
      float mnew = fmaxf(m_run, mx);
      float alpha = exp2f(m_run - mnew);
      float rsum = 0.0f;
      unsigned short* pr = Pw + (u * 16 + l16) * ALDP;
      for (int t = 0; t < 4; t++) {
        float p0 = exp2f(fmaf(s[u][t][0], sc2, -mnew));
        float p1 = exp2f(fmaf(s[u][t][1], sc2, -mnew));
        float p2 = exp2f(fmaf(s[u][t][2], sc2, -mnew));
        float p3 = exp2f(fmaf(s[u][t][3], sc2, -mnew));
        rsum += (p0 + p1) + (p2 + p3);
        ushort4 pk;
        pk.x = f2bf(p0); pk.y = f2bf(p1); pk.z = f2bf(p2); pk.w = f2bf(p3);
        *(ushort4*)(pr + t * 16 + quad * 4) = pk;   // P[q=l16][key=t*16+quad*4..]
      }
      rsum += __shfl_xor(rsum, 16, 64);
      rsum += __shfl_xor(rsum, 32, 64);
      l_run = l_run * alpha + rsum;
      m_run = mnew;
      if (u == 0) { m0 = m_run; l0 = l_run; } else { m1 = m_run; l1 = l_run; }
      float alr[4];
      for (int r = 0; r < 4; r++) alr[r] = __shfl(alpha, quad * 4 + r, 64);
      for (int j = 0; j < 4; j++)
        for (int r = 0; r < 4; r++) oacc[u][j][r] *= alr[r];
    }
    // wave-private P: writes complete before A-frag reads (in-order DS + drain)
    asm volatile("s_waitcnt lgkmcnt(0)" ::: "memory");
    // ---- PV: V-frags shared by both q-sets
    for (int ks = 0; ks < 2; ks++) {
      short8 af0 = *(const short8*)(Pw + l16 * ALDP + ks * 32 + quad * 8);
      short8 af1 = *(const short8*)(Pw + (16 + l16) * ALDP + ks * 32 + quad * 8);
      for (int j = 0; j < 4; j++) {
        short8 vf = *(const short8*)(&Vs[buf][(j * 16 + l16) * 64] +
                                     ((ks * 4 + quad) ^ sw) * 8);
        oacc[0][j] = __builtin_amdgcn_mfma_f32_16x16x32_bf16(af0, vf, oacc[0][j], 0, 0, 0);
        oacc[1][j] = __builtin_amdgcn_mfma_f32_16x16x32_bf16(af1, vf, oacc[1][j], 0, 0, 0);
      }
    }
  }

  float linv[2][4];
  for (int u = 0; u < 2; u++) {
    float lr = (u == 0) ? l0 : l1;
    for (int r = 0; r < 4; r++) linv[u][r] = 1.0f / __shfl(lr, quad * 4 + r, 64);
  }
  int bb = bh >> 4, hh = bh & 15;
  for (int u = 0; u < 2; u++)
    for (int j = 0; j < 4; j++)
      for (int r = 0; r < 4; r++) {
        size_t tok = (size_t)bb * 2048 + q0 + u * 16 + quad * 4 + r;
        ob[tok * 1024 + hh * 64 + j * 16 + l16] = f2bf(oacc[u][j][r] * linv[u][r]);
      }
}

// ---------------------------------------------------------------------------
// Launch
// ---------------------------------------------------------------------------
extern "C" void kernel_launch(void* const* d_in, const int* in_sizes, int n_in,
                              void* d_out, int out_size, void* d_ws, size_t ws_size,
                              hipStream_t stream) {
  (void)in_sizes; (void)n_in; (void)out_size; (void)ws_size;
  const float* x     = (const float*)d_in[0];
  const float* qkv_w = (const float*)d_in[1];
  const float* qkv_b = (const float*)d_in[2];
  const float* out_w = (const float*)d_in[3];
  const float* out_b = (const float*)d_in[4];
  const float* ff1_w = (const float*)d_in[5];
  const float* ff1_b = (const float*)d_in[6];
  const float* ff2_w = (const float*)d_in[7];
  const float* ff2_b = (const float*)d_in[8];
  const float* ln1_g = (const float*)d_in[9];
  const float* ln1_b = (const float*)d_in[10];
  const float* ln2_g = (const float*)d_in[11];
  const float* ln2_b = (const float*)d_in[12];
  float* out = (float*)d_out;
  char* ws = (char*)d_ws;

  const int M = 4096;  // B*S

  // ws layout (bytes)
  unsigned short* WQ = (unsigned short*)(ws + 0);           //  6,291,456
  unsigned short* WO = (unsigned short*)(ws + 6291456);     //  2,097,152
  unsigned short* W1 = (unsigned short*)(ws + 8388608);     //  8,388,608
  unsigned short* W2 = (unsigned short*)(ws + 16777216);    //  8,388,608
  unsigned short* Hb = (unsigned short*)(ws + 25165824);    //  8,388,608
  unsigned short* Qb = (unsigned short*)(ws + 33554432);    //  8,388,608
  unsigned short* Kb = (unsigned short*)(ws + 41943040);    //  8,388,608
  unsigned short* VT = (unsigned short*)(ws + 50331648);    //  8,388,608
  unsigned short* Ob = (unsigned short*)(ws + 58720256);    //  8,388,608
  float*          X1 = (float*)(ws + 67108864);             // 16,777,216
  unsigned short* Gb = (unsigned short*)(ws + 33554432);    // reuses Q/K/VT/O after out-proj
  // total ws footprint: 83,886,080 bytes (80 MB)

  // 1. weight conversions fp32 -> bf16
  conv_f32_bf16<<<3072, 256, 0, stream>>>(qkv_w, WQ, 786432);
  conv_f32_bf16<<<1024, 256, 0, stream>>>(out_w, WO, 262144);
  conv_f32_bf16<<<4096, 256, 0, stream>>>(ff1_w, W1, 1048576);
  conv_f32_bf16<<<4096, 256, 0, stream>>>(ff2_w, W2, 1048576);

  // 2. LN1: x -> Hb (bf16)
  ln_kernel<<<4096, 256, 0, stream>>>(x, ln1_g, ln1_b, Hb);

  // 3. QKV GEMM -> scatter q/k/vT
  gemm_bt<0><<<dim3(24, 32), 256, 0, stream>>>(Hb, WQ, qkv_b, M, 3072, 1024,
                                               nullptr, nullptr, nullptr, Qb, Kb, VT);

  // 4. attention -> Ob bf16 (B,S,E)
  attn_kernel<<<dim3(16, 32), 256, 0, stream>>>(Qb, Kb, VT, Ob);

  // 5. out-proj + residual: X1 = x + Ob@WO^T + out_b (fp32)
  gemm_bt<1><<<dim3(8, 32), 256, 0, stream>>>(Ob, WO, out_b, M, 1024, 1024,
                                              x, X1, nullptr, nullptr, nullptr, nullptr);

  // 6. LN2: X1 -> Hb (bf16)
  ln_kernel<<<4096, 256, 0, stream>>>(X1, ln2_g, ln2_b, Hb);

  // 7. FF1 + exact GELU: Gb = gelu(Hb@W1^T + ff1_b) bf16 (4096x4096)
  gemm_bt<2><<<dim3(32, 32), 256, 0, stream>>>(Hb, W1, ff1_b, M, 4096, 1024,
                                               nullptr, nullptr, Gb, nullptr, nullptr, nullptr);

  // 8. FF2 + residual: out = X1 + Gb@W2^T + ff2_b (fp32)
  gemm_bt<1><<<dim3(8, 32), 256, 0, stream>>>(Gb, W2, ff2_b, M, 1024, 4096,
                                              X1, out, nullptr, nullptr, nullptr, nullptr);
}